// Round 1
// baseline (178.315 us; speedup 1.0000x reference)
//
#include <hip/hip_runtime.h>
#include <math.h>

#define EMB 8
#define SEQ 1024
#define NBATCH 32
#define NROWS (NBATCH * SEQ)
#define LNEPS 1e-5f

// Closed-form quantum head: z_i = product of cos(x_j) over the Clifford-
// conjugated Pauli chain (even/odd prefix products; z_7 = full product).
__device__ __forceinline__ void qhead(const float xv[8], float z[8]) {
    float c[8];
#pragma unroll
    for (int j = 0; j < 8; ++j) c[j] = __cosf(xv[j]);
    float e0 = c[0];
    float o1 = c[1];
    float e2 = e0 * c[2];
    float o3 = o1 * c[3];
    float e4 = e2 * c[4];
    float o5 = o3 * c[5];
    float e6 = e4 * c[6];
    z[0] = e0; z[1] = o1; z[2] = e2; z[3] = o3;
    z[4] = e4; z[5] = o5; z[6] = e6;
    z[7] = e6 * o5 * c[7];
}

// x = emb[tokens] + posenc ; qkv = qhead(x)
__global__ __launch_bounds__(256) void embed_kernel(
    const int* __restrict__ tokens, const float* __restrict__ emb,
    float* __restrict__ x, float* __restrict__ qkv)
{
    int r = blockIdx.x * 256 + threadIdx.x;   // grid covers exactly NROWS
    int s = r & (SEQ - 1);
    int tok = tokens[r];
    const float* e = emb + (long)tok * EMB;
    float p = (float)s;
    float xv[8];
    xv[0] = e[0] + sinf(p);
    xv[1] = e[1] + cosf(p);
    xv[2] = e[2] + sinf(p * 0.1f);
    xv[3] = e[3] + cosf(p * 0.1f);
    xv[4] = e[4] + sinf(p * 0.01f);
    xv[5] = e[5] + cosf(p * 0.01f);
    xv[6] = e[6] + sinf(p * 0.001f);
    xv[7] = e[7] + cosf(p * 0.001f);
    float z[8]; qhead(xv, z);
    float4* xo = (float4*)(x + (long)r * 8);
    float4* qo = (float4*)(qkv + (long)r * 8);
    xo[0] = make_float4(xv[0], xv[1], xv[2], xv[3]);
    xo[1] = make_float4(xv[4], xv[5], xv[6], xv[7]);
    qo[0] = make_float4(z[0], z[1], z[2], z[3]);
    qo[1] = make_float4(z[4], z[5], z[6], z[7]);
}

// Per-batch attention + 8x8 projection + residual + LN1.  4 threads per
// query row (key phases interleaved mod 4 -> conflict-free LDS b128 reads).
__global__ __launch_bounds__(256) void attn_kernel(
    float* __restrict__ x, const float* __restrict__ qkv,
    const float* __restrict__ W, const float* __restrict__ bias,
    const float* __restrict__ gam, const float* __restrict__ bet)
{
    __shared__ float4 ks[SEQ * 2];   // 32 KB: qkv[b] as float4 pairs
    const int b = blockIdx.y;
    const int tid = threadIdx.x;

    const float4* src = (const float4*)(qkv + (long)b * SEQ * EMB);
    for (int i = tid; i < SEQ * 2; i += 256) ks[i] = src[i];
    __syncthreads();

    const int phase = tid & 3;
    const int row = blockIdx.x * 64 + (tid >> 2);
    const long grow = (long)b * SEQ + row;

    const float scale = 0.35355339059327373f;   // 1/sqrt(8)
    float4 q0 = ks[2 * row], q1 = ks[2 * row + 1];
    float q[8];
    q[0] = q0.x * scale; q[1] = q0.y * scale; q[2] = q0.z * scale; q[3] = q0.w * scale;
    q[4] = q1.x * scale; q[5] = q1.y * scale; q[6] = q1.z * scale; q[7] = q1.w * scale;

    float acc[8] = {0, 0, 0, 0, 0, 0, 0, 0};
    float sum = 0.f;
#pragma unroll 4
    for (int j = 0; j < SEQ / 4; ++j) {
        int k = (j << 2) | phase;
        float4 k0 = ks[2 * k], k1 = ks[2 * k + 1];
        float s = q[0] * k0.x + q[1] * k0.y + q[2] * k0.z + q[3] * k0.w
                + q[4] * k1.x + q[5] * k1.y + q[6] * k1.z + q[7] * k1.w;
        float ev = __expf(s);
        sum += ev;
        acc[0] += ev * k0.x; acc[1] += ev * k0.y; acc[2] += ev * k0.z; acc[3] += ev * k0.w;
        acc[4] += ev * k1.x; acc[5] += ev * k1.y; acc[6] += ev * k1.z; acc[7] += ev * k1.w;
    }
    // combine the 4 key-phases of this row
    sum += __shfl_xor(sum, 1); sum += __shfl_xor(sum, 2);
#pragma unroll
    for (int j = 0; j < 8; ++j) {
        acc[j] += __shfl_xor(acc[j], 1);
        acc[j] += __shfl_xor(acc[j], 2);
    }
    float inv = 1.0f / sum;
    float out[8];
#pragma unroll
    for (int j = 0; j < 8; ++j) out[j] = acc[j] * inv;

    // attn_out = out @ W + bias ; y = x + attn_out ; LN1
    float ao[8];
#pragma unroll
    for (int j = 0; j < 8; ++j) {
        float v = bias[j];
#pragma unroll
        for (int i = 0; i < 8; ++i) v += out[i] * W[i * 8 + j];
        ao[j] = v;
    }
    const float* xp = x + grow * 8;
    float y[8]; float m = 0.f;
#pragma unroll
    for (int j = 0; j < 8; ++j) { y[j] = xp[j] + ao[j]; m += y[j]; }
    m *= 0.125f;
    float var = 0.f;
#pragma unroll
    for (int j = 0; j < 8; ++j) { float d = y[j] - m; var += d * d; }
    var *= 0.125f;
    float rs = rsqrtf(var + LNEPS);
    if (phase == 0) {
        float o[8];
#pragma unroll
        for (int j = 0; j < 8; ++j) o[j] = gam[j] * (y[j] - m) * rs + bet[j];
        float4* xo = (float4*)(x + grow * 8);
        xo[0] = make_float4(o[0], o[1], o[2], o[3]);
        xo[1] = make_float4(o[4], o[5], o[6], o[7]);
    }
}

// FFN (8x8 -> qhead -> 8x8) + residual + LN2, fused with NEXT layer's qkv.
__global__ __launch_bounds__(256) void ffn_kernel(
    float* __restrict__ x, float* __restrict__ qkv,
    const float* __restrict__ W1, const float* __restrict__ b1,
    const float* __restrict__ W2, const float* __restrict__ b2,
    const float* __restrict__ gam, const float* __restrict__ bet)
{
    int r = blockIdx.x * 256 + threadIdx.x;
    const float4* xp = (const float4*)(x + (long)r * 8);
    float4 x0 = xp[0], x1 = xp[1];
    float xv[8] = {x0.x, x0.y, x0.z, x0.w, x1.x, x1.y, x1.z, x1.w};

    float h[8];
#pragma unroll
    for (int j = 0; j < 8; ++j) {
        float v = b1[j];
#pragma unroll
        for (int i = 0; i < 8; ++i) v += xv[i] * W1[i * 8 + j];
        h[j] = v;
    }
    float qf[8]; qhead(h, qf);
    float y[8]; float m = 0.f;
#pragma unroll
    for (int j = 0; j < 8; ++j) {
        float v = b2[j];
#pragma unroll
        for (int i = 0; i < 8; ++i) v += qf[i] * W2[i * 8 + j];
        y[j] = xv[j] + v;
        m += y[j];
    }
    m *= 0.125f;
    float var = 0.f;
#pragma unroll
    for (int j = 0; j < 8; ++j) { float d = y[j] - m; var += d * d; }
    var *= 0.125f;
    float rs = rsqrtf(var + LNEPS);
    float xn[8];
#pragma unroll
    for (int j = 0; j < 8; ++j) xn[j] = gam[j] * (y[j] - m) * rs + bet[j];
    float z[8]; qhead(xn, z);

    float4* xo = (float4*)(x + (long)r * 8);
    float4* qo = (float4*)(qkv + (long)r * 8);
    xo[0] = make_float4(xn[0], xn[1], xn[2], xn[3]);
    xo[1] = make_float4(xn[4], xn[5], xn[6], xn[7]);
    qo[0] = make_float4(z[0], z[1], z[2], z[3]);
    qo[1] = make_float4(z[4], z[5], z[6], z[7]);
}

// mean-pool over S + 8x10 classifier
__global__ __launch_bounds__(256) void pool_kernel(
    const float* __restrict__ x, const float* __restrict__ cls_w,
    const float* __restrict__ cls_b, float* __restrict__ out)
{
    __shared__ float ws[4][8];
    const int b = blockIdx.x;
    const int tid = threadIdx.x;
    float acc[8] = {0, 0, 0, 0, 0, 0, 0, 0};
    for (int s = tid; s < SEQ; s += 256) {
        const float4* p = (const float4*)(x + ((long)b * SEQ + s) * 8);
        float4 a0 = p[0], a1 = p[1];
        acc[0] += a0.x; acc[1] += a0.y; acc[2] += a0.z; acc[3] += a0.w;
        acc[4] += a1.x; acc[5] += a1.y; acc[6] += a1.z; acc[7] += a1.w;
    }
#pragma unroll
    for (int j = 0; j < 8; ++j) {
#pragma unroll
        for (int off = 1; off <= 32; off <<= 1) acc[j] += __shfl_xor(acc[j], off);
    }
    int wave = tid >> 6, lane = tid & 63;
    if (lane == 0) {
#pragma unroll
        for (int j = 0; j < 8; ++j) ws[wave][j] = acc[j];
    }
    __syncthreads();
    if (tid < 10) {
        float o = cls_b[tid];
#pragma unroll
        for (int j = 0; j < 8; ++j) {
            float pj = (ws[0][j] + ws[1][j] + ws[2][j] + ws[3][j]) * (1.0f / 1024.0f);
            o += pj * cls_w[j * 10 + tid];
        }
        out[b * 10 + tid] = o;
    }
}

extern "C" void kernel_launch(void* const* d_in, const int* in_sizes, int n_in,
                              void* d_out, int out_size, void* d_ws, size_t ws_size,
                              hipStream_t stream) {
    const int*   tokens = (const int*)d_in[0];
    const float* emb    = (const float*)d_in[1];
    const float* ln1_g  = (const float*)d_in[2];
    const float* ln1_b  = (const float*)d_in[3];
    const float* ln2_g  = (const float*)d_in[4];
    const float* ln2_b  = (const float*)d_in[5];
    const float* attn_w = (const float*)d_in[6];
    const float* attn_b = (const float*)d_in[7];
    const float* ffn_w1 = (const float*)d_in[8];
    const float* ffn_b1 = (const float*)d_in[9];
    const float* ffn_w2 = (const float*)d_in[10];
    const float* ffn_b2 = (const float*)d_in[11];
    const float* cls_w  = (const float*)d_in[12];
    const float* cls_b  = (const float*)d_in[13];

    float* x   = (float*)d_ws;                 // NROWS*8 f32 = 1 MB
    float* qkv = x + (long)NROWS * 8;          // NROWS*8 f32 = 1 MB

    embed_kernel<<<NROWS / 256, 256, 0, stream>>>(tokens, emb, x, qkv);
    for (int l = 0; l < 6; ++l) {
        attn_kernel<<<dim3(16, NBATCH), 256, 0, stream>>>(
            x, qkv, attn_w + l * 64, attn_b + l * 8, ln1_g + l * 8, ln1_b + l * 8);
        ffn_kernel<<<NROWS / 256, 256, 0, stream>>>(
            x, qkv, ffn_w1 + l * 64, ffn_b1 + l * 8, ffn_w2 + l * 64, ffn_b2 + l * 8,
            ln2_g + l * 8, ln2_b + l * 8);
    }
    pool_kernel<<<NBATCH, 256, 0, stream>>>(x, cls_w, cls_b, (float*)d_out);
}